// Round 7
// baseline (176.591 us; speedup 1.0000x reference)
//
#include <hip/hip_runtime.h>
#include <hip/hip_bf16.h>

// Ensemble Q-network, fused, transposed ([features x batch]).
//   h1^T = relu(W1^T x^T [+b1 via k=23]);  acc = W2^T h1^T + b2;  out = W3 . relu(acc).
// R2 (50.4us): BT=64, 4 waves/block, 4 blocks/CU. R3 FAILED (spill). R4 neutral.
// R5 FAILED (32x32 shape broke latency cover). R6 (48.5us): b1 folded into w1p k=23,
//     packed relu/dot, ping-pong A prefetch.
// R7: persistent blocks. Grid = 1024 blocks (4/CU exactly); each block loops 5
//     consecutive tiles. Rationale: MfmaUtil 42 / VALUBusy 47, stalls ~= block-start
//     x-load latency (x5 resident-set refills) + phase-locked co-resident blocks
//     (launched together -> MFMA-idle phases coincide). Persistence amortizes the
//     refills, lets block phases drift apart, and enables cross-tile prefetch:
//     next tile's bfr (xp) loads issue after layer-2 (regs dead there), hiding
//     under layer-3 + red barrier. XCD-chunked swizzle (1024=8x128, bijective)
//     gives each XCD ~1.25 consecutive nets of w2p/xp locality. #pragma unroll 1
//     on the tile loop keeps register pressure at R6's 64-VGPR budget.

typedef __attribute__((ext_vector_type(8))) short bf16x8;   // 8 bf16 (4 VGPRs)
typedef __attribute__((ext_vector_type(4))) float f32x4;    // MFMA C/D
typedef __attribute__((ext_vector_type(2))) float f32x2;

#define B_TOTAL 32768
#define NQ 10
#define HDIM 256
#define BT 64

#define XP_ELEMS  (B_TOTAL * 32)            // bf16 x, k-padded to 32 (k=23 slot = 1.0)
#define W1P_ELEMS (NQ * 16 * 64 * 8)        // [n][mtile16][lane64][j8]
#define W2P_ELEMS (NQ * 8 * 16 * 64 * 8)    // [n][kt8][mtile16][lane64][j8]

__device__ __forceinline__ unsigned short f2bf(float f) {
  unsigned int u = __float_as_uint(f);
  u = u + 0x7FFFu + ((u >> 16) & 1u);
  return (unsigned short)(u >> 16);
}

__device__ __forceinline__ unsigned int pk2bf(float a, float b) {
  union { __hip_bfloat162 h; unsigned int u; } cv;
  cv.h = __float22bfloat162_rn(make_float2(a, b));
  return cv.u;
}

// ---- single pack dispatch: x, W1^T(+b1), W2^T ----
__global__ void pack_all_kernel(const float* __restrict__ state,
                                const float* __restrict__ action,
                                const float* __restrict__ W1,
                                const float* __restrict__ b1,
                                const float* __restrict__ W2,
                                unsigned short* __restrict__ xp,
                                unsigned short* __restrict__ w1p,
                                unsigned short* __restrict__ w2p) {
  int t = blockIdx.x * 256 + threadIdx.x;   // 872 * 256 = 223232 exactly
  const int NX  = B_TOTAL * 4;              // 131072 uint4 chunks of xp
  const int NW1 = NQ * 16 * 64;             // 10240
  if (t < NX) {
    int b = t >> 2, seg = t & 3;
    unsigned short v[8];
    if (seg < 2) {
      const float* sp = state + (size_t)b * 17 + seg * 8;
#pragma unroll
      for (int j = 0; j < 8; j++) v[j] = f2bf(sp[j]);
    } else if (seg == 2) {
      v[0] = f2bf(state[(size_t)b * 17 + 16]);
#pragma unroll
      for (int j = 0; j < 6; j++) v[1 + j] = f2bf(action[(size_t)b * 6 + j]);
      v[7] = 0x3F80;                        // bf16(1.0): bias lane (k=23)
    } else {
#pragma unroll
      for (int j = 0; j < 8; j++) v[j] = 0;
    }
    *(uint4*)&xp[(size_t)t * 8] = *(const uint4*)v;
  } else if (t < NX + NW1) {
    int u = t - NX;
    int lane = u & 63, mt = (u >> 6) & 15, n = u >> 10;
    int m = lane & 15, q = lane >> 4;
    int outc = mt * 16 + m;
    unsigned short v[8];
#pragma unroll
    for (int j = 0; j < 8; j++) {
      int k = q * 8 + j;
      v[j] = (k < 23) ? f2bf(W1[(n * 23 + k) * 256 + outc])
           : (k == 23) ? f2bf(b1[n * 256 + outc]) : (unsigned short)0;
    }
    *(uint4*)&w1p[(size_t)u * 8] = *(const uint4*)v;
  } else {
    int u = t - NX - NW1;                   // < 81920
    int lane = u & 63, mt = (u >> 6) & 15, kt = (u >> 10) & 7, n = u >> 13;
    int m = lane & 15, q = lane >> 4;
    int outc = mt * 16 + m;
    unsigned short v[8];
#pragma unroll
    for (int j = 0; j < 8; j++) {
      int h = kt * 32 + q * 8 + j;
      v[j] = f2bf(W2[((size_t)(n * 256 + h)) * 256 + outc]);
    }
    *(uint4*)&w2p[(size_t)u * 8] = *(const uint4*)v;
  }
}

// ---- fused MLP: 1024 persistent blocks x 256 threads (4 waves), 4 blocks/CU ----
// wave w: channels [w*64, w*64+64); all waves share the tile's 64 batch cols.
// Each block processes 5 consecutive tiles (5120 tiles total).
__global__ __launch_bounds__(256, 4) void fused_ensemble_kernel(
    const unsigned short* __restrict__ xp,
    const unsigned short* __restrict__ w1p,
    const unsigned short* __restrict__ w2p,
    const float* __restrict__ b2,
    const float* __restrict__ W3,
    const float* __restrict__ b3,
    float* __restrict__ out) {
  __shared__ __align__(16) unsigned short hs[32 * BT * 8];  // 32 KB, [ch/8][col][8]
  __shared__ float red[4 * 64];                             // 1 KB cross-wave reduce

  const int tid = threadIdx.x;
  const int lane = tid & 63;
  const int w = tid >> 6;       // 0..3: channels [w*64, w*64+64)
  const int m = lane & 15;
  const int q = lane >> 4;

  // XCD-chunked swizzle: 1024 = 8 XCDs x 128 chunks (bijective). XCD k works
  // tiles [k*640, (k+1)*640) -> ~1.25 consecutive nets per XCD (w2p/xp L2-local).
  const int bid = blockIdx.x;
  const int tile0 = ((bid & 7) * 128 + (bid >> 3)) * 5;

  f32x4 acc[4][4];   // [mt][nt]: ch = w*64 + mt*16 + q*4 + r, col = nt*16 + m
  bf16x8 bfr[4];     // layer-1 B frags; prefetched for tile t+1 during layer 3

  // ---- prologue: B-frags for the first tile ----
  {
    int row0 = (tile0 & 511) * BT;
#pragma unroll
    for (int nt = 0; nt < 4; nt++)
      bfr[nt] = *(const bf16x8*)(xp + (size_t)(row0 + nt * 16 + m) * 32 + q * 8);
  }

#pragma unroll 1
  for (int tt = 0; tt < 5; ++tt) {
    const int t = tile0 + tt;
    const int n = t >> 9;
    const int row0 = (t & 511) * BT;

    // ---- layer 1: single K-step (K=32; k=23 carries the bias via xp=1.0) ----
    {
      bf16x8 af1[4];
#pragma unroll
      for (int mt = 0; mt < 4; mt++)
        af1[mt] = *(const bf16x8*)(w1p + (((size_t)n * 16 + w * 4 + mt) * 64 + lane) * 8);
#pragma unroll
      for (int mt = 0; mt < 4; mt++)
#pragma unroll
        for (int nt = 0; nt < 4; nt++) acc[mt][nt] = (f32x4)0.0f;
      __builtin_amdgcn_s_setprio(1);
#pragma unroll
      for (int nt = 0; nt < 4; nt++)
#pragma unroll
        for (int mt = 0; mt < 4; mt++)
          acc[mt][nt] = __builtin_amdgcn_mfma_f32_16x16x32_bf16(af1[mt], bfr[nt], acc[mt][nt], 0, 0, 0);
      __builtin_amdgcn_s_setprio(0);
    }

    // ---- epilogue 1: relu (v_pk_max) -> h1 bf16 frag-chunk layout ----
#pragma unroll
    for (int mt = 0; mt < 4; mt++) {
      int kq = w * 8 + mt * 2 + (q >> 1);
      int joff = (q & 1) * 4;
#pragma unroll
      for (int nt = 0; nt < 4; nt++) {
        int col = nt * 16 + m;
        f32x4 a = __builtin_elementwise_max(acc[mt][nt], (f32x4)0.0f);
        uint2 wv;
        wv.x = pk2bf(a.x, a.y);
        wv.y = pk2bf(a.z, a.w);
        *(uint2*)&hs[((size_t)kq * BT + col) * 8 + joff] = wv;
      }
    }

    // ---- layer-2 first A-frags + bias: issue BEFORE the barrier ----
    const unsigned short* w2n = w2p + (size_t)n * (8 * 16 * 64 * 8);
    bf16x8 afb[2][4];                       // ping-pong A prefetch (no copies)
#pragma unroll
    for (int mt = 0; mt < 4; mt++)
      afb[0][mt] = *(const bf16x8*)(w2n + (((size_t)w * 4 + mt) * 64 + lane) * 8);
    f32x4 b2v[4];
#pragma unroll
    for (int mt = 0; mt < 4; mt++)
      b2v[mt] = *(const f32x4*)&b2[n * HDIM + (w * 4 + mt) * 16 + q * 4];
    __syncthreads();

    // ---- layer 2: 8 K-steps, A-frags streamed from L2 with 1-deep prefetch ----
    {
#pragma unroll
      for (int mt = 0; mt < 4; mt++)
#pragma unroll
        for (int nt = 0; nt < 4; nt++) acc[mt][nt] = b2v[mt];
#pragma unroll
      for (int kt = 0; kt < 8; kt++) {
        if (kt < 7) {
#pragma unroll
          for (int mt = 0; mt < 4; mt++)
            afb[(kt + 1) & 1][mt] =
                *(const bf16x8*)(w2n + (((size_t)(kt + 1) * 16 + w * 4 + mt) * 64 + lane) * 8);
        }
        bf16x8 bq[4];
#pragma unroll
        for (int nt = 0; nt < 4; nt++)
          bq[nt] = *(const bf16x8*)&hs[(((size_t)kt * 4 + q) * BT + nt * 16 + m) * 8];
        __builtin_amdgcn_s_setprio(1);
#pragma unroll
        for (int nt = 0; nt < 4; nt++)
#pragma unroll
          for (int mt = 0; mt < 4; mt++)
            acc[mt][nt] = __builtin_amdgcn_mfma_f32_16x16x32_bf16(afb[kt & 1][mt], bq[nt],
                                                                 acc[mt][nt], 0, 0, 0);
        __builtin_amdgcn_s_setprio(0);
      }
    }

    // ---- prefetch next tile's B-frags (regs dead during layer 2; hides
    //      ~600cyc global latency under layer 3 + red barrier) ----
    if (tt < 4) {
      int row0n = ((t + 1) & 511) * BT;
#pragma unroll
      for (int nt = 0; nt < 4; nt++)
        bfr[nt] = *(const bf16x8*)(xp + (size_t)(row0n + nt * 16 + m) * 32 + q * 8);
    }

    // ---- layer 3 in-register: p[col] = sum_ch relu(acc_ch) * W3[ch]; reduce ----
    {
      f32x4 w3v[4];
#pragma unroll
      for (int mt = 0; mt < 4; mt++)
        w3v[mt] = *(const f32x4*)&W3[n * HDIM + (w * 4 + mt) * 16 + q * 4];
      float p[4];
#pragma unroll
      for (int nt = 0; nt < 4; nt++) {
        f32x2 s2 = (f32x2)0.0f;
#pragma unroll
        for (int mt = 0; mt < 4; mt++) {
          f32x4 a = __builtin_elementwise_max(acc[mt][nt], (f32x4)0.0f);
          s2 += a.lo * w3v[mt].lo;          // v_pk_fma_f32
          s2 += a.hi * w3v[mt].hi;
        }
        float s = s2.x + s2.y;
        s += __shfl_xor(s, 16, 64);   // reduce q within wave (channels)
        s += __shfl_xor(s, 32, 64);
        p[nt] = s;
      }
      if (q == 0) {
#pragma unroll
        for (int nt = 0; nt < 4; nt++) red[w * 64 + nt * 16 + m] = p[nt];
      }
      __syncthreads();
      if (tid < BT) {
        float s = b3[n];
#pragma unroll
        for (int c = 0; c < 4; c++) s += red[c * 64 + tid];
        out[(size_t)n * B_TOTAL + row0 + tid] = s;
      }
    }
  }
}

extern "C" void kernel_launch(void* const* d_in, const int* in_sizes, int n_in,
                              void* d_out, int out_size, void* d_ws, size_t ws_size,
                              hipStream_t stream) {
  const float* state  = (const float*)d_in[0];
  const float* action = (const float*)d_in[1];
  const float* W1 = (const float*)d_in[2];
  const float* b1 = (const float*)d_in[3];
  const float* W2 = (const float*)d_in[4];
  const float* b2 = (const float*)d_in[5];
  const float* W3 = (const float*)d_in[6];
  const float* b3 = (const float*)d_in[7];
  float* out = (float*)d_out;

  unsigned short* xp  = (unsigned short*)d_ws;                                    // 2,097,152 B
  unsigned short* w1p = (unsigned short*)((char*)d_ws + (size_t)XP_ELEMS * 2);    //   163,840 B
  unsigned short* w2p = (unsigned short*)((char*)d_ws + (size_t)(XP_ELEMS + W1P_ELEMS) * 2); // 1,310,720 B

  pack_all_kernel<<<872, 256, 0, stream>>>(state, action, W1, b1, W2, xp, w1p, w2p);
  fused_ensemble_kernel<<<1024, 256, 0, stream>>>(
      xp, w1p, w2p, b2, W3, b3, out);
}

// Round 8
// 123.486 us; speedup vs baseline: 1.4300x; 1.4300x over previous
//
#include <hip/hip_runtime.h>
#include <hip/hip_bf16.h>

// Ensemble Q-network, fused, transposed ([features x batch]).
//   h1^T = relu(W1^T x^T [+b1 via k=23]);  acc = W2^T h1^T + b2;  out = W3 . relu(acc).
// R2 (50.4us): BT=64, 4 waves/block, 4 blocks/CU. R3 FAILED (deep pipeline -> spill).
// R4 neutral. R5 FAILED (32x32 shape broke latency cover). R6 (48.5us): b1 folded
// into w1p k=23, packed relu/dot, ping-pong A prefetch. R7 FAILED (persistent tile
// loop -> loop-carried regs over the exact 128-reg budget -> spill, 213MB fetch).
// Lesson: zero loop-carried register headroom at 4 waves/SIMD.
// R8: atomic tail. out pre-initialized to b3 in the pack kernel; layer-3 partials
//     atomicAdd'ed directly from q==0 lanes. Deletes the red LDS round-trip, the
//     second __syncthreads, and the 64-of-256-thread serial final sum -> one
//     barrier per tile, fewer phase-lock points. Register-neutral.

typedef __attribute__((ext_vector_type(8))) short bf16x8;   // 8 bf16 (4 VGPRs)
typedef __attribute__((ext_vector_type(4))) float f32x4;    // MFMA C/D
typedef __attribute__((ext_vector_type(2))) float f32x2;

#define B_TOTAL 32768
#define NQ 10
#define HDIM 256
#define BT 64

#define XP_ELEMS  (B_TOTAL * 32)            // bf16 x, k-padded to 32 (k=23 slot = 1.0)
#define W1P_ELEMS (NQ * 16 * 64 * 8)        // [n][mtile16][lane64][j8]
#define W2P_ELEMS (NQ * 8 * 16 * 64 * 8)    // [n][kt8][mtile16][lane64][j8]

__device__ __forceinline__ unsigned short f2bf(float f) {
  unsigned int u = __float_as_uint(f);
  u = u + 0x7FFFu + ((u >> 16) & 1u);
  return (unsigned short)(u >> 16);
}

__device__ __forceinline__ unsigned int pk2bf(float a, float b) {
  union { __hip_bfloat162 h; unsigned int u; } cv;
  cv.h = __float22bfloat162_rn(make_float2(a, b));
  return cv.u;
}

// ---- single pack dispatch: x, W1^T(+b1), W2^T, out=b3 ----
__global__ void pack_all_kernel(const float* __restrict__ state,
                                const float* __restrict__ action,
                                const float* __restrict__ W1,
                                const float* __restrict__ b1,
                                const float* __restrict__ W2,
                                const float* __restrict__ b3,
                                unsigned short* __restrict__ xp,
                                unsigned short* __restrict__ w1p,
                                unsigned short* __restrict__ w2p,
                                float* __restrict__ out) {
  int t = blockIdx.x * 256 + threadIdx.x;   // 1192 * 256 = 305152 exactly
  const int NX  = B_TOTAL * 4;              // 131072 uint4 chunks of xp
  const int NW1 = NQ * 16 * 64;             // 10240
  const int NW2 = NQ * 8 * 16 * 64;         // 81920
  if (t < NX) {
    int b = t >> 2, seg = t & 3;
    unsigned short v[8];
    if (seg < 2) {
      const float* sp = state + (size_t)b * 17 + seg * 8;
#pragma unroll
      for (int j = 0; j < 8; j++) v[j] = f2bf(sp[j]);
    } else if (seg == 2) {
      v[0] = f2bf(state[(size_t)b * 17 + 16]);
#pragma unroll
      for (int j = 0; j < 6; j++) v[1 + j] = f2bf(action[(size_t)b * 6 + j]);
      v[7] = 0x3F80;                        // bf16(1.0): bias lane (k=23)
    } else {
#pragma unroll
      for (int j = 0; j < 8; j++) v[j] = 0;
    }
    *(uint4*)&xp[(size_t)t * 8] = *(const uint4*)v;
  } else if (t < NX + NW1) {
    int u = t - NX;
    int lane = u & 63, mt = (u >> 6) & 15, n = u >> 10;
    int m = lane & 15, q = lane >> 4;
    int outc = mt * 16 + m;
    unsigned short v[8];
#pragma unroll
    for (int j = 0; j < 8; j++) {
      int k = q * 8 + j;
      v[j] = (k < 23) ? f2bf(W1[(n * 23 + k) * 256 + outc])
           : (k == 23) ? f2bf(b1[n * 256 + outc]) : (unsigned short)0;
    }
    *(uint4*)&w1p[(size_t)u * 8] = *(const uint4*)v;
  } else if (t < NX + NW1 + NW2) {
    int u = t - NX - NW1;                   // < 81920
    int lane = u & 63, mt = (u >> 6) & 15, kt = (u >> 10) & 7, n = u >> 13;
    int m = lane & 15, q = lane >> 4;
    int outc = mt * 16 + m;
    unsigned short v[8];
#pragma unroll
    for (int j = 0; j < 8; j++) {
      int h = kt * 32 + q * 8 + j;
      v[j] = f2bf(W2[((size_t)(n * 256 + h)) * 256 + outc]);
    }
    *(uint4*)&w2p[(size_t)u * 8] = *(const uint4*)v;
  } else {
    // out init: out[n][*] = b3[n]; 81920 f32x4 chunks (32768 f32 per net, 4|32768)
    int u = t - NX - NW1 - NW2;             // < 81920
    int n = u >> 13;                        // 8192 chunks per net
    float b = b3[n];
    float4 v = make_float4(b, b, b, b);
    *(float4*)&out[(size_t)u * 4] = v;
  }
}

// ---- fused MLP: 5120 blocks x 256 threads (4 waves), 4 blocks/CU ----
// wave w: channels [w*64, w*64+64); all waves share the block's 64 batch cols
__global__ __launch_bounds__(256, 4) void fused_ensemble_kernel(
    const unsigned short* __restrict__ xp,
    const unsigned short* __restrict__ w1p,
    const unsigned short* __restrict__ w2p,
    const float* __restrict__ b2,
    const float* __restrict__ W3,
    float* __restrict__ out) {
  __shared__ __align__(16) unsigned short hs[32 * BT * 8];  // 32 KB, [ch/8][col][8]

  const int tid = threadIdx.x;
  const int lane = tid & 63;
  const int w = tid >> 6;       // 0..3: channels [w*64, w*64+64)
  const int m = lane & 15;
  const int q = lane >> 4;

  const int n = blockIdx.x >> 9;            // 512 tiles per net
  const int row0 = (blockIdx.x & 511) * BT;

  f32x4 acc[4][4];   // [mt][nt]: ch = w*64 + mt*16 + q*4 + r, col = nt*16 + m

  // ---- layer 1: single K-step (K=32; k=23 carries the bias via xp=1.0) ----
  {
    bf16x8 af1[4], bfr[4];
#pragma unroll
    for (int nt = 0; nt < 4; nt++) {
      int col = row0 + nt * 16 + m;         // global batch row
      bfr[nt] = *(const bf16x8*)(xp + (size_t)col * 32 + q * 8);
    }
#pragma unroll
    for (int mt = 0; mt < 4; mt++)
      af1[mt] = *(const bf16x8*)(w1p + (((size_t)n * 16 + w * 4 + mt) * 64 + lane) * 8);
#pragma unroll
    for (int mt = 0; mt < 4; mt++)
#pragma unroll
      for (int nt = 0; nt < 4; nt++) acc[mt][nt] = (f32x4)0.0f;
    __builtin_amdgcn_s_setprio(1);
#pragma unroll
    for (int nt = 0; nt < 4; nt++)
#pragma unroll
      for (int mt = 0; mt < 4; mt++)
        acc[mt][nt] = __builtin_amdgcn_mfma_f32_16x16x32_bf16(af1[mt], bfr[nt], acc[mt][nt], 0, 0, 0);
    __builtin_amdgcn_s_setprio(0);
  }

  // ---- epilogue 1: relu (v_pk_max) -> h1 bf16 frag-chunk layout ----
#pragma unroll
  for (int mt = 0; mt < 4; mt++) {
    int kq = w * 8 + mt * 2 + (q >> 1);
    int joff = (q & 1) * 4;
#pragma unroll
    for (int nt = 0; nt < 4; nt++) {
      int col = nt * 16 + m;
      f32x4 a = __builtin_elementwise_max(acc[mt][nt], (f32x4)0.0f);
      uint2 wv;
      wv.x = pk2bf(a.x, a.y);
      wv.y = pk2bf(a.z, a.w);
      *(uint2*)&hs[((size_t)kq * BT + col) * 8 + joff] = wv;
    }
  }

  // ---- layer-2 first A-frags + bias: issue BEFORE the barrier ----
  const unsigned short* w2n = w2p + (size_t)n * (8 * 16 * 64 * 8);
  bf16x8 afb[2][4];                         // ping-pong A prefetch (no copies)
#pragma unroll
  for (int mt = 0; mt < 4; mt++)
    afb[0][mt] = *(const bf16x8*)(w2n + (((size_t)w * 4 + mt) * 64 + lane) * 8);
  f32x4 b2v[4];
#pragma unroll
  for (int mt = 0; mt < 4; mt++)
    b2v[mt] = *(const f32x4*)&b2[n * HDIM + (w * 4 + mt) * 16 + q * 4];
  __syncthreads();

  // ---- layer 2: 8 K-steps, A-frags streamed from L2 with 1-deep prefetch ----
  {
#pragma unroll
    for (int mt = 0; mt < 4; mt++)
#pragma unroll
      for (int nt = 0; nt < 4; nt++) acc[mt][nt] = b2v[mt];
#pragma unroll
    for (int kt = 0; kt < 8; kt++) {
      if (kt < 7) {
#pragma unroll
        for (int mt = 0; mt < 4; mt++)
          afb[(kt + 1) & 1][mt] =
              *(const bf16x8*)(w2n + (((size_t)(kt + 1) * 16 + w * 4 + mt) * 64 + lane) * 8);
      }
      bf16x8 bfr[4];
#pragma unroll
      for (int nt = 0; nt < 4; nt++)
        bfr[nt] = *(const bf16x8*)&hs[(((size_t)kt * 4 + q) * BT + nt * 16 + m) * 8];
      __builtin_amdgcn_s_setprio(1);
#pragma unroll
      for (int nt = 0; nt < 4; nt++)
#pragma unroll
        for (int mt = 0; mt < 4; mt++)
          acc[mt][nt] = __builtin_amdgcn_mfma_f32_16x16x32_bf16(afb[kt & 1][mt], bfr[nt],
                                                               acc[mt][nt], 0, 0, 0);
      __builtin_amdgcn_s_setprio(0);
    }
  }

  // ---- layer 3: p[col] = sum_ch relu(acc_ch) * W3[ch]; wave-reduce + atomicAdd ----
  // (out pre-initialized to b3 by the pack kernel; no red LDS, no second barrier)
  {
    f32x4 w3v[4];
#pragma unroll
    for (int mt = 0; mt < 4; mt++)
      w3v[mt] = *(const f32x4*)&W3[n * HDIM + (w * 4 + mt) * 16 + q * 4];
    float p[4];
#pragma unroll
    for (int nt = 0; nt < 4; nt++) {
      f32x2 s2 = (f32x2)0.0f;
#pragma unroll
      for (int mt = 0; mt < 4; mt++) {
        f32x4 a = __builtin_elementwise_max(acc[mt][nt], (f32x4)0.0f);
        s2 += a.lo * w3v[mt].lo;            // v_pk_fma_f32
        s2 += a.hi * w3v[mt].hi;
      }
      float s = s2.x + s2.y;
      s += __shfl_xor(s, 16, 64);   // reduce q within wave (channels)
      s += __shfl_xor(s, 32, 64);
      p[nt] = s;
    }
    if (q == 0) {
      float* ob = out + (size_t)n * B_TOTAL + row0 + m;
#pragma unroll
      for (int nt = 0; nt < 4; nt++)
        atomicAdd(ob + nt * 16, p[nt]);
    }
  }
}

extern "C" void kernel_launch(void* const* d_in, const int* in_sizes, int n_in,
                              void* d_out, int out_size, void* d_ws, size_t ws_size,
                              hipStream_t stream) {
  const float* state  = (const float*)d_in[0];
  const float* action = (const float*)d_in[1];
  const float* W1 = (const float*)d_in[2];
  const float* b1 = (const float*)d_in[3];
  const float* W2 = (const float*)d_in[4];
  const float* b2 = (const float*)d_in[5];
  const float* W3 = (const float*)d_in[6];
  const float* b3 = (const float*)d_in[7];
  float* out = (float*)d_out;

  unsigned short* xp  = (unsigned short*)d_ws;                                    // 2,097,152 B
  unsigned short* w1p = (unsigned short*)((char*)d_ws + (size_t)XP_ELEMS * 2);    //   163,840 B
  unsigned short* w2p = (unsigned short*)((char*)d_ws + (size_t)(XP_ELEMS + W1P_ELEMS) * 2); // 1,310,720 B

  pack_all_kernel<<<1192, 256, 0, stream>>>(state, action, W1, b1, W2, b3,
                                            xp, w1p, w2p, out);
  fused_ensemble_kernel<<<NQ * (B_TOTAL / BT), 256, 0, stream>>>(
      xp, w1p, w2p, b2, W3, out);
}

// Round 9
// 118.377 us; speedup vs baseline: 1.4918x; 1.0432x over previous
//
#include <hip/hip_runtime.h>
#include <hip/hip_bf16.h>

// Ensemble Q-network, fused, transposed ([features x batch]).
//   h1^T = relu(W1^T x^T [+b1 via k=23]);  acc = W2^T h1^T + b2;  out = W3 . relu(acc).
// R2 (50.4us): BT=64, 4 waves/block, 4 blocks/CU. R3 FAILED (deep pipeline at 128-reg
// budget -> spill). R4 neutral. R5 FAILED (32x32: same work, +15us pure dep-stall).
// R6 (48.5us, best): b1 folded into w1p k=23, packed relu/dot, ping-pong A prefetch.
// R7 FAILED (persistent loop -> spill). R8 FAILED (atomic tail +4us RMW stalls).
// Synthesis: R5/R8 regressions were pure STALL (absolute MFMA/VALU time constant);
// R6's missing ~35% of wall is per-wave dep stall, unfixable inside 128 regs/wave.
// R9: trade TLP for registers. __launch_bounds__(256,3) -> 3 waves/SIMD, 170-reg
//     budget (12 waves/CU, 3 blocks/CU, LDS 99KB/CU). Headroom spent on the one
//     pipeline R3 couldn't afford: double-buffered LDS B-frags (+32 VGPR) on top of
//     ping-pong A-prefetch -> ds_read(kt+1) issues before MFMA(kt), removing the
//     ~120cyc LDS serialization per K-step. Math/layout byte-identical to R6.

typedef __attribute__((ext_vector_type(8))) short bf16x8;   // 8 bf16 (4 VGPRs)
typedef __attribute__((ext_vector_type(4))) float f32x4;    // MFMA C/D
typedef __attribute__((ext_vector_type(2))) float f32x2;

#define B_TOTAL 32768
#define NQ 10
#define HDIM 256
#define BT 64

#define XP_ELEMS  (B_TOTAL * 32)            // bf16 x, k-padded to 32 (k=23 slot = 1.0)
#define W1P_ELEMS (NQ * 16 * 64 * 8)        // [n][mtile16][lane64][j8]
#define W2P_ELEMS (NQ * 8 * 16 * 64 * 8)    // [n][kt8][mtile16][lane64][j8]

__device__ __forceinline__ unsigned short f2bf(float f) {
  unsigned int u = __float_as_uint(f);
  u = u + 0x7FFFu + ((u >> 16) & 1u);
  return (unsigned short)(u >> 16);
}

__device__ __forceinline__ unsigned int pk2bf(float a, float b) {
  union { __hip_bfloat162 h; unsigned int u; } cv;
  cv.h = __float22bfloat162_rn(make_float2(a, b));
  return cv.u;
}

// ---- single pack dispatch: x, W1^T(+b1), W2^T ----
__global__ void pack_all_kernel(const float* __restrict__ state,
                                const float* __restrict__ action,
                                const float* __restrict__ W1,
                                const float* __restrict__ b1,
                                const float* __restrict__ W2,
                                unsigned short* __restrict__ xp,
                                unsigned short* __restrict__ w1p,
                                unsigned short* __restrict__ w2p) {
  int t = blockIdx.x * 256 + threadIdx.x;   // 872 * 256 = 223232 exactly
  const int NX  = B_TOTAL * 4;              // 131072 uint4 chunks of xp
  const int NW1 = NQ * 16 * 64;             // 10240
  if (t < NX) {
    int b = t >> 2, seg = t & 3;
    unsigned short v[8];
    if (seg < 2) {
      const float* sp = state + (size_t)b * 17 + seg * 8;
#pragma unroll
      for (int j = 0; j < 8; j++) v[j] = f2bf(sp[j]);
    } else if (seg == 2) {
      v[0] = f2bf(state[(size_t)b * 17 + 16]);
#pragma unroll
      for (int j = 0; j < 6; j++) v[1 + j] = f2bf(action[(size_t)b * 6 + j]);
      v[7] = 0x3F80;                        // bf16(1.0): bias lane (k=23)
    } else {
#pragma unroll
      for (int j = 0; j < 8; j++) v[j] = 0;
    }
    *(uint4*)&xp[(size_t)t * 8] = *(const uint4*)v;
  } else if (t < NX + NW1) {
    int u = t - NX;
    int lane = u & 63, mt = (u >> 6) & 15, n = u >> 10;
    int m = lane & 15, q = lane >> 4;
    int outc = mt * 16 + m;
    unsigned short v[8];
#pragma unroll
    for (int j = 0; j < 8; j++) {
      int k = q * 8 + j;
      v[j] = (k < 23) ? f2bf(W1[(n * 23 + k) * 256 + outc])
           : (k == 23) ? f2bf(b1[n * 256 + outc]) : (unsigned short)0;
    }
    *(uint4*)&w1p[(size_t)u * 8] = *(const uint4*)v;
  } else {
    int u = t - NX - NW1;                   // < 81920
    int lane = u & 63, mt = (u >> 6) & 15, kt = (u >> 10) & 7, n = u >> 13;
    int m = lane & 15, q = lane >> 4;
    int outc = mt * 16 + m;
    unsigned short v[8];
#pragma unroll
    for (int j = 0; j < 8; j++) {
      int h = kt * 32 + q * 8 + j;
      v[j] = f2bf(W2[((size_t)(n * 256 + h)) * 256 + outc]);
    }
    *(uint4*)&w2p[(size_t)u * 8] = *(const uint4*)v;
  }
}

// ---- fused MLP: 5120 blocks x 256 threads (4 waves), 3 blocks/CU (170-reg budget) ----
// wave w: channels [w*64, w*64+64); all waves share the block's 64 batch cols
__global__ __launch_bounds__(256, 3) void fused_ensemble_kernel(
    const unsigned short* __restrict__ xp,
    const unsigned short* __restrict__ w1p,
    const unsigned short* __restrict__ w2p,
    const float* __restrict__ b2,
    const float* __restrict__ W3,
    const float* __restrict__ b3,
    float* __restrict__ out) {
  __shared__ __align__(16) unsigned short hs[32 * BT * 8];  // 32 KB, [ch/8][col][8]
  __shared__ float red[4 * 64];                             // 1 KB cross-wave reduce

  const int tid = threadIdx.x;
  const int lane = tid & 63;
  const int w = tid >> 6;       // 0..3: channels [w*64, w*64+64)
  const int m = lane & 15;
  const int q = lane >> 4;

  const int n = blockIdx.x >> 9;            // 512 tiles per net
  const int row0 = (blockIdx.x & 511) * BT;

  f32x4 acc[4][4];   // [mt][nt]: ch = w*64 + mt*16 + q*4 + r, col = nt*16 + m

  // ---- layer 1: single K-step (K=32; k=23 carries the bias via xp=1.0) ----
  {
    bf16x8 af1[4], bfr[4];
#pragma unroll
    for (int nt = 0; nt < 4; nt++) {
      int col = row0 + nt * 16 + m;         // global batch row
      bfr[nt] = *(const bf16x8*)(xp + (size_t)col * 32 + q * 8);
    }
#pragma unroll
    for (int mt = 0; mt < 4; mt++)
      af1[mt] = *(const bf16x8*)(w1p + (((size_t)n * 16 + w * 4 + mt) * 64 + lane) * 8);
#pragma unroll
    for (int mt = 0; mt < 4; mt++)
#pragma unroll
      for (int nt = 0; nt < 4; nt++) acc[mt][nt] = (f32x4)0.0f;
    __builtin_amdgcn_s_setprio(1);
#pragma unroll
    for (int nt = 0; nt < 4; nt++)
#pragma unroll
      for (int mt = 0; mt < 4; mt++)
        acc[mt][nt] = __builtin_amdgcn_mfma_f32_16x16x32_bf16(af1[mt], bfr[nt], acc[mt][nt], 0, 0, 0);
    __builtin_amdgcn_s_setprio(0);
  }

  // ---- epilogue 1: relu (v_pk_max) -> h1 bf16 frag-chunk layout ----
#pragma unroll
  for (int mt = 0; mt < 4; mt++) {
    int kq = w * 8 + mt * 2 + (q >> 1);
    int joff = (q & 1) * 4;
#pragma unroll
    for (int nt = 0; nt < 4; nt++) {
      int col = nt * 16 + m;
      f32x4 a = __builtin_elementwise_max(acc[mt][nt], (f32x4)0.0f);
      uint2 wv;
      wv.x = pk2bf(a.x, a.y);
      wv.y = pk2bf(a.z, a.w);
      *(uint2*)&hs[((size_t)kq * BT + col) * 8 + joff] = wv;
    }
  }

  // ---- layer-2 first A-frags + bias: issue BEFORE the barrier ----
  const unsigned short* w2n = w2p + (size_t)n * (8 * 16 * 64 * 8);
  bf16x8 afb[2][4];                         // ping-pong A prefetch (global/L2)
#pragma unroll
  for (int mt = 0; mt < 4; mt++)
    afb[0][mt] = *(const bf16x8*)(w2n + (((size_t)w * 4 + mt) * 64 + lane) * 8);
  f32x4 b2v[4];
#pragma unroll
  for (int mt = 0; mt < 4; mt++)
    b2v[mt] = *(const f32x4*)&b2[n * HDIM + (w * 4 + mt) * 16 + q * 4];
  __syncthreads();

  // ---- layer 2: 8 K-steps; A ping-pong from L2, B double-buffered from LDS ----
  {
    bf16x8 bfb[2][4];                       // double-buffered B frags (LDS)
#pragma unroll
    for (int nt = 0; nt < 4; nt++)
      bfb[0][nt] = *(const bf16x8*)&hs[(((size_t)0 * 4 + q) * BT + nt * 16 + m) * 8];
#pragma unroll
    for (int mt = 0; mt < 4; mt++)
#pragma unroll
      for (int nt = 0; nt < 4; nt++) acc[mt][nt] = b2v[mt];
#pragma unroll
    for (int kt = 0; kt < 8; kt++) {
      if (kt < 7) {
#pragma unroll
        for (int mt = 0; mt < 4; mt++)
          afb[(kt + 1) & 1][mt] =
              *(const bf16x8*)(w2n + (((size_t)(kt + 1) * 16 + w * 4 + mt) * 64 + lane) * 8);
#pragma unroll
        for (int nt = 0; nt < 4; nt++)
          bfb[(kt + 1) & 1][nt] =
              *(const bf16x8*)&hs[(((size_t)(kt + 1) * 4 + q) * BT + nt * 16 + m) * 8];
      }
      __builtin_amdgcn_s_setprio(1);
#pragma unroll
      for (int nt = 0; nt < 4; nt++)
#pragma unroll
        for (int mt = 0; mt < 4; mt++)
          acc[mt][nt] = __builtin_amdgcn_mfma_f32_16x16x32_bf16(afb[kt & 1][mt], bfb[kt & 1][nt],
                                                               acc[mt][nt], 0, 0, 0);
      __builtin_amdgcn_s_setprio(0);
    }
  }

  // ---- layer 3 in-register: p[col] = sum_ch relu(acc_ch) * W3[ch]; reduce ----
  {
    f32x4 w3v[4];
#pragma unroll
    for (int mt = 0; mt < 4; mt++)
      w3v[mt] = *(const f32x4*)&W3[n * HDIM + (w * 4 + mt) * 16 + q * 4];
    float p[4];
#pragma unroll
    for (int nt = 0; nt < 4; nt++) {
      f32x2 s2 = (f32x2)0.0f;
#pragma unroll
      for (int mt = 0; mt < 4; mt++) {
        f32x4 a = __builtin_elementwise_max(acc[mt][nt], (f32x4)0.0f);
        s2 += a.lo * w3v[mt].lo;            // v_pk_fma_f32
        s2 += a.hi * w3v[mt].hi;
      }
      float s = s2.x + s2.y;
      s += __shfl_xor(s, 16, 64);   // reduce q within wave (channels)
      s += __shfl_xor(s, 32, 64);
      p[nt] = s;
    }
    if (q == 0) {
#pragma unroll
      for (int nt = 0; nt < 4; nt++) red[w * 64 + nt * 16 + m] = p[nt];
    }
    __syncthreads();
    if (tid < BT) {
      float s = b3[n];
#pragma unroll
      for (int c = 0; c < 4; c++) s += red[c * 64 + tid];
      out[(size_t)n * B_TOTAL + row0 + tid] = s;
    }
  }
}

extern "C" void kernel_launch(void* const* d_in, const int* in_sizes, int n_in,
                              void* d_out, int out_size, void* d_ws, size_t ws_size,
                              hipStream_t stream) {
  const float* state  = (const float*)d_in[0];
  const float* action = (const float*)d_in[1];
  const float* W1 = (const float*)d_in[2];
  const float* b1 = (const float*)d_in[3];
  const float* W2 = (const float*)d_in[4];
  const float* b2 = (const float*)d_in[5];
  const float* W3 = (const float*)d_in[6];
  const float* b3 = (const float*)d_in[7];
  float* out = (float*)d_out;

  unsigned short* xp  = (unsigned short*)d_ws;                                    // 2,097,152 B
  unsigned short* w1p = (unsigned short*)((char*)d_ws + (size_t)XP_ELEMS * 2);    //   163,840 B
  unsigned short* w2p = (unsigned short*)((char*)d_ws + (size_t)(XP_ELEMS + W1P_ELEMS) * 2); // 1,310,720 B

  pack_all_kernel<<<872, 256, 0, stream>>>(state, action, W1, b1, W2, xp, w1p, w2p);
  fused_ensemble_kernel<<<NQ * (B_TOTAL / BT), 256, 0, stream>>>(
      xp, w1p, w2p, b2, W3, b3, out);
}